// Round 1
// baseline (1183.670 us; speedup 1.0000x reference)
//
#include <hip/hip_runtime.h>
#include <math.h>

#pragma clang fp contract(off)

#define NB 16
#define NC 80
#define NTOT 17064
#define TOPK 1000
#define NBINS 8192
#define CAP 4096
#define MAXDET 100

struct Ptrs {
    const float* lg[5];
    const float* bb[5];
    const float* ct[5];
};

__device__ __forceinline__ float sigmoidf_(float x) {
    return 1.0f / (1.0f + expf(-x));
}

__device__ __forceinline__ void level_of(int n, int& l, int& hw, int& W,
                                         int& stride, int& half, int& HW) {
    if (n < 12800)      { l = 0; hw = n;         W = 128; stride = 8;   half = 4;  HW = 12800; }
    else if (n < 16000) { l = 1; hw = n - 12800; W = 64;  stride = 16;  half = 8;  HW = 3200;  }
    else if (n < 16800) { l = 2; hw = n - 16000; W = 32;  stride = 32;  half = 16; HW = 800;   }
    else if (n < 17008) { l = 3; hw = n - 16800; W = 16;  stride = 64;  half = 32; HW = 208;   }
    else                { l = 4; hw = n - 17008; W = 8;   stride = 128; half = 64; HW = 56;    }
}

// Pass 1: histogram of candidate score bit-patterns (top 13 bits) per batch.
__global__ void k_hist(Ptrs p, unsigned* hist) {
    int t = blockIdx.x * blockDim.x + threadIdx.x;
    if (t >= NB * NTOT) return;
    int b = t / NTOT, n = t % NTOT;
    int l, hw, W, stride, half, HW;
    level_of(n, l, hw, W, stride, half, HW);
    float cen = sigmoidf_(p.ct[l][(size_t)b * HW + hw]);
    const float* lg = p.lg[l] + (size_t)b * NC * HW + hw;
    unsigned* h = hist + (size_t)b * NBINS;
    for (int c = 0; c < NC; ++c) {
        float x = lg[(size_t)c * HW];
        if (x > -2.95f) {                    // logit(0.05) = -2.9444; margin-safe prefilter
            float cls = sigmoidf_(x);
            if (cls > 0.05f) {
                float comb = cls * cen;
                atomicAdd(&h[__float_as_uint(comb) >> 19], 1u);
            }
        }
    }
}

// Pass 2: find threshold bin T[b]: highest bin where suffix count reaches TOPK.
__global__ void k_thresh(const unsigned* hist, unsigned* T) {
    __shared__ unsigned a[256];
    __shared__ int Tf;
    int b = blockIdx.x, tid = threadIdx.x;
    if (tid == 0) Tf = 0;
    const unsigned* h = hist + (size_t)b * NBINS;
    int base = tid * 32;
    unsigned mysum = 0;
    for (int i = 0; i < 32; ++i) mysum += h[base + i];
    a[tid] = mysum;
    __syncthreads();
    for (int off = 1; off < 256; off <<= 1) {
        unsigned v = (tid + off < 256) ? a[tid + off] : 0u;
        __syncthreads();
        a[tid] += v;
        __syncthreads();
    }
    unsigned excl = a[tid] - mysum;          // count in all higher chunks
    if (excl < TOPK && excl + mysum >= TOPK) {
        unsigned running = excl;
        for (int bin = base + 31; bin >= base; --bin) {
            running += h[bin];
            if (running >= TOPK) { Tf = bin; break; }
        }
    }
    __syncthreads();
    if (tid == 0) T[b] = (unsigned)Tf;
}

// Pass 3: compact (score_bits, ~idx) keys for bin >= T.
__global__ void k_compact(Ptrs p, const unsigned* Tthr, unsigned* cnt,
                          unsigned long long* buf) {
    int t = blockIdx.x * blockDim.x + threadIdx.x;
    if (t >= NB * NTOT) return;
    int b = t / NTOT, n = t % NTOT;
    int l, hw, W, stride, half, HW;
    level_of(n, l, hw, W, stride, half, HW);
    float cen = sigmoidf_(p.ct[l][(size_t)b * HW + hw]);
    const float* lg = p.lg[l] + (size_t)b * NC * HW + hw;
    unsigned Tb = Tthr[b];
    for (int c = 0; c < NC; ++c) {
        float x = lg[(size_t)c * HW];
        if (x > -2.95f) {
            float cls = sigmoidf_(x);
            if (cls > 0.05f) {
                float comb = cls * cen;
                unsigned bits = __float_as_uint(comb);
                if ((bits >> 19) >= Tb) {
                    unsigned pos = atomicAdd(&cnt[b], 1u);
                    if (pos < CAP) {
                        unsigned idx = (unsigned)(n * NC + c);
                        buf[(size_t)b * CAP + pos] =
                            ((unsigned long long)bits << 32) | (0xFFFFFFFFu - idx);
                    }
                }
            }
        }
    }
}

// Pass 4: per-batch bitonic sort (descending), keeping exact lax.top_k order
// (value desc, index asc via complemented idx in low bits). Pads (0) sort last.
__global__ void __launch_bounds__(256) k_sort(const unsigned* cnt,
                                              const unsigned long long* buf,
                                              unsigned long long* topk) {
    __shared__ unsigned long long keys[CAP];   // 32 KiB
    int b = blockIdx.x, tid = threadIdx.x;
    unsigned M = cnt[b];
    if (M > CAP) M = CAP;
    for (int i = tid; i < CAP; i += 256)
        keys[i] = (i < (int)M) ? buf[(size_t)b * CAP + i] : 0ULL;
    __syncthreads();
    for (int k = 2; k <= CAP; k <<= 1) {
        for (int j = k >> 1; j > 0; j >>= 1) {
            for (int i = tid; i < CAP; i += 256) {
                int ixj = i ^ j;
                if (ixj > i) {
                    unsigned long long va = keys[i], vb = keys[ixj];
                    bool desc = ((i & k) == 0);
                    if (desc ? (va < vb) : (va > vb)) { keys[i] = vb; keys[ixj] = va; }
                }
            }
            __syncthreads();
        }
    }
    for (int r = tid; r < TOPK; r += 256)
        topk[(size_t)b * TOPK + r] = keys[r];
}

// Pass 5: decode boxes + greedy class-aware NMS, one block per batch.
__global__ void __launch_bounds__(256) k_nms(Ptrs p, const unsigned long long* topk,
                                             const float* im_info, float* out) {
    __shared__ float nb0[TOPK], nb1[TOPK], nb2[TOPK], nb3[TOPK];
    __shared__ float area[TOPK], sc[TOPK];
    __shared__ float ox1[TOPK], oy1[TOPK], ox2[TOPK], oy2[TOPK], clsf[TOPK];
    __shared__ float rs[256];
    __shared__ int   ri[256];
    __shared__ int   pick;
    int b = blockIdx.x, tid = threadIdx.x;
    float Him = im_info[b * 2 + 0], Wim = im_info[b * 2 + 1];
    float xmax = Wim - 1.0f, ymax = Him - 1.0f;

    for (int r = tid; r < TOPK; r += 256) {
        unsigned long long key = topk[(size_t)b * TOPK + r];
        unsigned sb = (unsigned)(key >> 32);
        if (sb == 0) {
            nb0[r] = nb1[r] = nb2[r] = nb3[r] = 0.f;
            area[r] = 0.f; sc[r] = 0.f;
            ox1[r] = oy1[r] = ox2[r] = oy2[r] = 0.f; clsf[r] = 0.f;
        } else {
            unsigned idx = 0xFFFFFFFFu - (unsigned)(key & 0xFFFFFFFFu);
            float val = __uint_as_float(sb);
            int n = idx / NC, c = idx - n * NC;
            int l, hw, W, stride, half, HW;
            level_of(n, l, hw, W, stride, half, HW);
            int wx = hw % W, hy = hw / W;
            float locx = (float)(wx * stride + half);
            float locy = (float)(hy * stride + half);
            const float* bb = p.bb[l] + (size_t)b * 4 * HW + hw;
            float r0 = bb[0], r1 = bb[(size_t)HW], r2 = bb[(size_t)2 * HW], r3 = bb[(size_t)3 * HW];
            float x1 = locx - r0, y1 = locy - r1, x2 = locx + r2, y2 = locy + r3;
            x1 = fminf(fmaxf(x1, 0.f), xmax);
            y1 = fminf(fmaxf(y1, 0.f), ymax);
            x2 = fminf(fmaxf(x2, 0.f), xmax);
            y2 = fminf(fmaxf(y2, 0.f), ymax);
            float s = sqrtf(val + 1e-12f);
            float off = (float)c * 10000.0f;
            ox1[r] = x1; oy1[r] = y1; ox2[r] = x2; oy2[r] = y2; clsf[r] = (float)c;
            sc[r] = s;
            float a0 = x1 + off, a1 = y1 + off, a2 = x2 + off, a3 = y2 + off;
            nb0[r] = a0; nb1[r] = a1; nb2[r] = a2; nb3[r] = a3;
            area[r] = fmaxf(a2 - a0, 0.f) * fmaxf(a3 - a1, 0.f);
        }
    }
    __syncthreads();

    for (int it = 0; it < MAXDET; ++it) {
        // argmax with lowest-index tie-break (matches jnp.argmax)
        float best = -__builtin_inff();
        int bi = 0x7FFFFFFF;
        for (int r = tid; r < TOPK; r += 256) {
            float s = sc[r];
            if (s > best || (s == best && r < bi)) { best = s; bi = r; }
        }
        rs[tid] = best; ri[tid] = bi;
        __syncthreads();
        for (int step = 128; step > 0; step >>= 1) {
            if (tid < step) {
                float s2 = rs[tid + step]; int i2 = ri[tid + step];
                if (s2 > rs[tid] || (s2 == rs[tid] && i2 < ri[tid])) {
                    rs[tid] = s2; ri[tid] = i2;
                }
            }
            __syncthreads();
        }
        if (tid == 0) {
            int i = ri[0];
            float s = rs[0];
            pick = i;
            float* o = out + ((size_t)b * MAXDET + it) * 6;
            if (s > 0.f) {
                o[0] = ox1[i]; o[1] = oy1[i]; o[2] = ox2[i]; o[3] = oy2[i];
                o[4] = s;      o[5] = clsf[i];
            } else {
                o[0] = 0.f; o[1] = 0.f; o[2] = 0.f; o[3] = 0.f; o[4] = 0.f; o[5] = 0.f;
            }
        }
        __syncthreads();
        int i = pick;
        float bi0 = nb0[i], bi1 = nb1[i], bi2 = nb2[i], bi3 = nb3[i], ai = area[i];
        for (int r = tid; r < TOPK; r += 256) {
            float xx1 = fmaxf(bi0, nb0[r]);
            float yy1 = fmaxf(bi1, nb1[r]);
            float xx2 = fminf(bi2, nb2[r]);
            float yy2 = fminf(bi3, nb3[r]);
            float inter = fmaxf(xx2 - xx1, 0.f) * fmaxf(yy2 - yy1, 0.f);
            float iou = inter / (((ai + area[r]) - inter) + 1e-9f);
            if (iou >= 0.6f || r == i) sc[r] = -__builtin_inff();
        }
        __syncthreads();
    }
}

extern "C" void kernel_launch(void* const* d_in, const int* in_sizes, int n_in,
                              void* d_out, int out_size, void* d_ws, size_t ws_size,
                              hipStream_t stream) {
    Ptrs p;
    for (int l = 0; l < 5; ++l) {
        p.lg[l] = (const float*)d_in[3 * l + 0];
        p.bb[l] = (const float*)d_in[3 * l + 1];
        p.ct[l] = (const float*)d_in[3 * l + 2];
    }
    const float* im_info = (const float*)d_in[15];
    float* out = (float*)d_out;

    unsigned char* w = (unsigned char*)d_ws;
    unsigned* hist           = (unsigned*)(w);                 // 16*8192*4 = 524288 B
    unsigned* cnt            = (unsigned*)(w + 524288);        // 64 B
    unsigned* T              = (unsigned*)(w + 524352);        // 64 B
    unsigned long long* buf  = (unsigned long long*)(w + 524416);   // 16*4096*8 = 524288 B
    unsigned long long* topk = (unsigned long long*)(w + 1048704);  // 16*1000*8 = 128000 B

    hipMemsetAsync(w, 0, 524352, stream);  // zero hist + cnt

    int total = NB * NTOT;
    int blocks = (total + 255) / 256;
    k_hist<<<blocks, 256, 0, stream>>>(p, hist);
    k_thresh<<<NB, 256, 0, stream>>>(hist, T);
    k_compact<<<blocks, 256, 0, stream>>>(p, T, cnt, buf);
    k_sort<<<NB, 256, 0, stream>>>(cnt, buf, topk);
    k_nms<<<NB, 256, 0, stream>>>(p, topk, im_info, out);
}